// Round 1
// baseline (333.093 us; speedup 1.0000x reference)
//
#include <hip/hip_runtime.h>

// Problem geometry (compile-time constants, from the reference)
constexpr int Bn = 8, Cn = 4, Dn = 64, Hn = 128, Wn = 64;

// Grid spacings (computed in double, folded to float factors)
constexpr double DXd = (2.0 - -0.5) / 63.0;   // 2.5/63
constexpr double DYd = (0.5 - -0.5) / 127.0;  // 1/127
constexpr double DZd = (0.3 - -0.5) / 63.0;   // 0.8/63

__device__ __constant__ const float I2DX = (float)(0.5 / DXd);   // 12.6
__device__ __constant__ const float I2DY = (float)(0.5 / DYd);   // 63.5
__device__ __constant__ const float I2DZ = (float)(0.5 / DZd);   // 39.375
__device__ __constant__ const float IDX2 = (float)(1.0 / (DXd * DXd)); // 635.04
__device__ __constant__ const float IDY2 = (float)(1.0 / (DYd * DYd)); // 16129
__device__ __constant__ const float IDZ2 = (float)(1.0 / (DZd * DZd)); // 6201.5625
__device__ __constant__ const float INV_RE = 1.0e-6f;

// Per-term weight / count  (weights: field 1, ct 10, cont 1, mom 1, noslip 10, inlet 5, outlet 1)
__device__ __constant__ const float CF  = (float)(1.0  / (8.0 * 4.0 * 64.0 * 128.0 * 64.0)); // 1/16777216
__device__ __constant__ const float CCT = (float)(10.0 / 8.0);
__device__ __constant__ const float CC  = (float)(1.0  / (8.0 * 62.0 * 126.0 * 62.0));       // 1/3874752
__device__ __constant__ const float CM  = (float)(1.0  / (8.0 * 62.0 * 126.0 * 62.0));
__device__ __constant__ const float CN  = (float)(10.0 / (8.0 * 64.0 * 128.0 * 64.0));       // 10/4194304
__device__ __constant__ const float CI  = (float)(5.0  / (8.0 * 64.0 * 128.0));              // 5/65536
__device__ __constant__ const float CO  = (float)(1.0  / (8.0 * 64.0 * 128.0));              // 1/65536

__global__ __launch_bounds__(256) void fno3d_loss_kernel(
    const float* __restrict__ field,
    const float* __restrict__ ct,
    const float* __restrict__ gt_field,
    const float* __restrict__ gt_ct,
    const float* __restrict__ sdf,
    float* __restrict__ out)
{
    const int w  = threadIdx.x;                 // 0..63  (lane index == w -> coalesced)
    const int h  = blockIdx.y * 4 + threadIdx.y; // 0..127
    const int bd = blockIdx.z;                  // b*64 + d
    const int b  = bd >> 6;
    const int d  = bd & 63;

    // signed strides (need negative offsets for stencil)
    const long sH = Wn;                    // 64
    const long sD = (long)Hn * Wn;         // 8192
    const long sC = (long)Dn * Hn * Wn;    // 524288
    const long sB = (long)Cn * sC;         // 2097152

    const long sp   = (long)d * sD + (long)h * sH + w;
    const float* F = field    + (long)b * sB + sp;
    const float* G = gt_field + (long)b * sB + sp;

    const float u  = F[0];
    const float v  = F[sC];
    const float wv = F[2 * sC];
    const float p  = F[3 * sC];

    float acc;
    {
        const float d0 = u  - G[0];
        const float d1 = v  - G[sC];
        const float d2 = wv - G[2 * sC];
        const float d3 = p  - G[3 * sC];
        acc = CF * (d0 * d0 + d1 * d1 + d2 * d2 + d3 * d3);
    }

    const float s = sdf[(long)b * sC + sp];

    // no-slip: solid = sdf <= 0
    if (s <= 0.f) acc += CN * (u * u + v * v + wv * wv);

    // inlet: w == 0
    if (w == 0) {
        const float du = u - 1.0f;
        acc += CI * (du * du + v * v + wv * wv);
    }

    // outlet: w == W-1 (uses w-1 neighbor)
    if (w == Wn - 1) {
        const float a = u  - F[-1];
        const float bq = v  - F[sC - 1];
        const float c = wv - F[2 * sC - 1];
        acc += CO * (a * a + bq * bq + c * c);
    }

    // interior continuity + momentum, masked by fluid = sdf > 0
    if (s > 0.f && w >= 1 && w < Wn - 1 && h >= 1 && h < Hn - 1 && d >= 1 && d < Dn - 1) {
        const float uxp = F[1],          uxm = F[-1];
        const float uyp = F[sH],         uym = F[-sH];
        const float uzp = F[sD],         uzm = F[-sD];

        const float vxp = F[sC + 1],     vxm = F[sC - 1];
        const float vyp = F[sC + sH],    vym = F[sC - sH];
        const float vzp = F[sC + sD],    vzm = F[sC - sD];

        const float wxp = F[2 * sC + 1],  wxm = F[2 * sC - 1];
        const float wyp = F[2 * sC + sH], wym = F[2 * sC - sH];
        const float wzp = F[2 * sC + sD], wzm = F[2 * sC - sD];

        const float pxp = F[3 * sC + 1],  pxm = F[3 * sC - 1];
        const float pyp = F[3 * sC + sH], pym = F[3 * sC - sH];
        const float pzp = F[3 * sC + sD], pzm = F[3 * sC - sD];

        const float du_dx = (uxp - uxm) * I2DX;
        const float du_dy = (uyp - uym) * I2DY;
        const float du_dz = (uzp - uzm) * I2DZ;
        const float dv_dx = (vxp - vxm) * I2DX;
        const float dv_dy = (vyp - vym) * I2DY;
        const float dv_dz = (vzp - vzm) * I2DZ;
        const float dw_dx = (wxp - wxm) * I2DX;
        const float dw_dy = (wyp - wym) * I2DY;
        const float dw_dz = (wzp - wzm) * I2DZ;
        const float dp_dx = (pxp - pxm) * I2DX;
        const float dp_dy = (pyp - pym) * I2DY;
        const float dp_dz = (pzp - pzm) * I2DZ;

        const float div = du_dx + dv_dy + dw_dz;
        acc += CC * div * div;

        const float lap_u = (uxp - 2.f * u  + uxm) * IDX2 + (uyp - 2.f * u  + uym) * IDY2 + (uzp - 2.f * u  + uzm) * IDZ2;
        const float lap_v = (vxp - 2.f * v  + vxm) * IDX2 + (vyp - 2.f * v  + vym) * IDY2 + (vzp - 2.f * v  + vzm) * IDZ2;
        const float lap_w = (wxp - 2.f * wv + wxm) * IDX2 + (wyp - 2.f * wv + wym) * IDY2 + (wzp - 2.f * wv + wzm) * IDZ2;

        const float rx = u * du_dx + v * du_dy + wv * du_dz + dp_dx - INV_RE * lap_u;
        const float ry = u * dv_dx + v * dv_dy + wv * dv_dz + dp_dy - INV_RE * lap_v;
        const float rz = u * dw_dx + v * dw_dy + wv * dw_dz + dp_dz - INV_RE * lap_w;

        acc += CM * (rx * rx + ry * ry + rz * rz);
    }

    // ct loss: one designated thread
    if (bd == 0 && blockIdx.y == 0 && threadIdx.x == 0 && threadIdx.y == 0) {
        float t = 0.f;
        for (int i = 0; i < Bn; ++i) {
            const float dc = ct[i] - gt_ct[i];
            t += dc * dc;
        }
        acc += CCT * t;
    }

    // reduction: wave64 shfl -> LDS -> one atomic per block
    for (int off = 32; off > 0; off >>= 1)
        acc += __shfl_down(acc, off);

    __shared__ float wsum[4];
    const int tid  = threadIdx.y * 64 + threadIdx.x;
    const int wid  = tid >> 6;
    const int lane = tid & 63;
    if (lane == 0) wsum[wid] = acc;
    __syncthreads();
    if (tid == 0) {
        atomicAdd(out, wsum[0] + wsum[1] + wsum[2] + wsum[3]);
    }
}

extern "C" void kernel_launch(void* const* d_in, const int* in_sizes, int n_in,
                              void* d_out, int out_size, void* d_ws, size_t ws_size,
                              hipStream_t stream) {
    const float* field    = (const float*)d_in[0];
    const float* ct       = (const float*)d_in[1];
    const float* gt_field = (const float*)d_in[2];
    const float* gt_ct    = (const float*)d_in[3];
    const float* sdf      = (const float*)d_in[4];
    float* out = (float*)d_out;

    // d_out is re-poisoned before every timed call; zero it on-stream.
    hipMemsetAsync(out, 0, (size_t)out_size * sizeof(float), stream);

    dim3 block(64, 4, 1);
    dim3 grid(1, Hn / 4, Bn * Dn);
    hipLaunchKernelGGL(fno3d_loss_kernel, grid, block, 0, stream,
                       field, ct, gt_field, gt_ct, sdf, out);
}

// Round 3
// 179.994 us; speedup vs baseline: 1.8506x; 1.8506x over previous
//
#include <hip/hip_runtime.h>

// Geometry (compile-time, from reference)
constexpr int Bn = 8, Dn = 64, Hn = 128, Wn = 64;
constexpr int sH = Wn;                 // 64
constexpr int sD = Hn * Wn;            // 8192
constexpr int sC = Dn * Hn * Wn;       // 524288
constexpr int sB = 4 * sC;             // 2097152  (fits int; max addr 16.7M floats)

// Grid spacings
constexpr double DXd = (2.0 - -0.5) / 63.0;
constexpr double DYd = (0.5 - -0.5) / 127.0;
constexpr double DZd = (0.3 - -0.5) / 63.0;

constexpr float I2DX = (float)(0.5 / DXd);
constexpr float I2DY = (float)(0.5 / DYd);
constexpr float I2DZ = (float)(0.5 / DZd);
constexpr float IDX2 = (float)(1.0 / (DXd * DXd));
constexpr float IDY2 = (float)(1.0 / (DYd * DYd));
constexpr float IDZ2 = (float)(1.0 / (DZd * DZd));
constexpr float INV_RE = 1.0e-6f;

// weights / counts
constexpr float CF  = (float)(1.0  / (8.0 * 4.0 * 64.0 * 128.0 * 64.0));
constexpr float CCT = (float)(10.0 / 8.0);
constexpr float CCM = (float)(1.0  / (8.0 * 62.0 * 126.0 * 62.0));  // cont & mom share weight+count
constexpr float CN  = (float)(10.0 / (8.0 * 64.0 * 128.0 * 64.0));
constexpr float CI  = (float)(5.0  / (8.0 * 64.0 * 128.0));
constexpr float CO  = (float)(1.0  / (8.0 * 64.0 * 128.0));

__device__ __forceinline__ float4 ld4(const float* __restrict__ p, int off) {
    return *reinterpret_cast<const float4*>(p + off);
}

__global__ __launch_bounds__(256) void fno3d_loss_kernel(
    const float* __restrict__ field,
    const float* __restrict__ ct,
    const float* __restrict__ gt_field,
    const float* __restrict__ gt_ct,
    const float* __restrict__ sdf,
    float* __restrict__ out)
{
    const int x  = threadIdx.x;            // 0..15 (w quad)
    const int ty = threadIdx.y;            // 0..3
    const int tz = threadIdx.z;            // 0..3
    const int h  = blockIdx.y * 4 + ty;    // 0..127
    const int bdt = blockIdx.z;            // b*16 + d_tile
    const int b  = bdt >> 4;
    const int d  = (bdt & 15) * 4 + tz;    // 0..63
    const int w0 = x * 4;

    const float* Fb = field    + b * sB;
    const float* Gb = gt_field + b * sB;
    const float* Sb = sdf      + b * sC;

    const int ctr = d * sD + h * sH + w0;
    const int hm = (h > 0)      ? h - 1 : h;
    const int hp = (h < Hn - 1) ? h + 1 : h;
    const int dm = (d > 0)      ? d - 1 : d;
    const int dp = (d < Dn - 1) ? d + 1 : d;
    const int oyp = d * sD + hp * sH + w0;
    const int oym = d * sD + hm * sH + w0;
    const int ozp = dp * sD + h * sH + w0;
    const int ozm = dm * sD + h * sH + w0;

    // ---- issue ALL loads up front (25 x dwordx4, unconditional) ----
    const float4 cu = ld4(Fb, ctr);
    const float4 cv = ld4(Fb, sC + ctr);
    const float4 cw = ld4(Fb, 2 * sC + ctr);
    const float4 cp = ld4(Fb, 3 * sC + ctr);

    const float4 gu = ld4(Gb, ctr);
    const float4 gv = ld4(Gb, sC + ctr);
    const float4 gw = ld4(Gb, 2 * sC + ctr);
    const float4 gp = ld4(Gb, 3 * sC + ctr);

    const float4 sv = ld4(Sb, ctr);

    const float4 uyp = ld4(Fb, oyp),          uym = ld4(Fb, oym);
    const float4 vyp = ld4(Fb, sC + oyp),     vym = ld4(Fb, sC + oym);
    const float4 wyp = ld4(Fb, 2 * sC + oyp), wym = ld4(Fb, 2 * sC + oym);
    const float4 pyp = ld4(Fb, 3 * sC + oyp), pym = ld4(Fb, 3 * sC + oym);

    const float4 uzp = ld4(Fb, ozp),          uzm = ld4(Fb, ozm);
    const float4 vzp = ld4(Fb, sC + ozp),     vzm = ld4(Fb, sC + ozm);
    const float4 wzp = ld4(Fb, 2 * sC + ozp), wzm = ld4(Fb, 2 * sC + ozm);
    const float4 pzp = ld4(Fb, 3 * sC + ozp), pzm = ld4(Fb, 3 * sC + ozm);

    // ---- x-neighbors across lanes (16-lane row groups inside wave64) ----
    const float uLs = __shfl_up(cu.w, 1), uRs = __shfl_down(cu.x, 1);
    const float vLs = __shfl_up(cv.w, 1), vRs = __shfl_down(cv.x, 1);
    const float wLs = __shfl_up(cw.w, 1), wRs = __shfl_down(cw.x, 1);
    const float pLs = __shfl_up(cp.w, 1), pRs = __shfl_down(cp.x, 1);

    const float* au  = reinterpret_cast<const float*>(&cu);
    const float* av  = reinterpret_cast<const float*>(&cv);
    const float* aw  = reinterpret_cast<const float*>(&cw);
    const float* ap  = reinterpret_cast<const float*>(&cp);
    const float* agu = reinterpret_cast<const float*>(&gu);
    const float* agv = reinterpret_cast<const float*>(&gv);
    const float* agw = reinterpret_cast<const float*>(&gw);
    const float* agp = reinterpret_cast<const float*>(&gp);
    const float* as_ = reinterpret_cast<const float*>(&sv);
    const float* auyp = reinterpret_cast<const float*>(&uyp);
    const float* auym = reinterpret_cast<const float*>(&uym);
    const float* avyp = reinterpret_cast<const float*>(&vyp);
    const float* avym = reinterpret_cast<const float*>(&vym);
    const float* awyp = reinterpret_cast<const float*>(&wyp);
    const float* awym = reinterpret_cast<const float*>(&wym);
    const float* apyp = reinterpret_cast<const float*>(&pyp);
    const float* apym = reinterpret_cast<const float*>(&pym);
    const float* auzp = reinterpret_cast<const float*>(&uzp);
    const float* auzm = reinterpret_cast<const float*>(&uzm);
    const float* avzp = reinterpret_cast<const float*>(&vzp);
    const float* avzm = reinterpret_cast<const float*>(&vzm);
    const float* awzp = reinterpret_cast<const float*>(&wzp);
    const float* awzm = reinterpret_cast<const float*>(&wzm);
    const float* apzp = reinterpret_cast<const float*>(&pzp);
    const float* apzm = reinterpret_cast<const float*>(&pzm);

    const bool hIn = (h >= 1) & (h <= Hn - 2);
    const bool dIn = (d >= 1) & (d <= Dn - 2);

    float acc = 0.f;

    #pragma unroll
    for (int e = 0; e < 4; ++e) {
        const int w = w0 + e;
        const float u = au[e], v = av[e], wq = aw[e], pq = ap[e];

        // field MSE
        {
            const float d0 = u  - agu[e];
            const float d1 = v  - agv[e];
            const float d2 = wq - agw[e];
            const float d3 = pq - agp[e];
            acc += CF * (d0 * d0 + d1 * d1 + d2 * d2 + d3 * d3);
        }

        const float s = as_[e];

        // no-slip (solid)
        acc += ((s <= 0.f) ? CN : 0.f) * (u * u + v * v + wq * wq);

        // inlet (w==0)
        {
            const float du = u - 1.0f;
            acc += ((w == 0) ? CI : 0.f) * (du * du + v * v + wq * wq);
        }

        // interior cont+mom (branch-free, clamped neighbors masked out)
        const float uxm = (e == 0) ? uLs : au[e - 1];
        const float uxp = (e == 3) ? uRs : au[e + 1];
        const float vxm = (e == 0) ? vLs : av[e - 1];
        const float vxp = (e == 3) ? vRs : av[e + 1];
        const float wxm = (e == 0) ? wLs : aw[e - 1];
        const float wxp = (e == 3) ? wRs : aw[e + 1];
        const float pxm = (e == 0) ? pLs : ap[e - 1];
        const float pxp = (e == 3) ? pRs : ap[e + 1];

        const float du_dx = (uxp - uxm) * I2DX;
        const float du_dy = (auyp[e] - auym[e]) * I2DY;
        const float du_dz = (auzp[e] - auzm[e]) * I2DZ;
        const float dv_dx = (vxp - vxm) * I2DX;
        const float dv_dy = (avyp[e] - avym[e]) * I2DY;
        const float dv_dz = (avzp[e] - avzm[e]) * I2DZ;
        const float dw_dx = (wxp - wxm) * I2DX;
        const float dw_dy = (awyp[e] - awym[e]) * I2DY;
        const float dw_dz = (awzp[e] - awzm[e]) * I2DZ;
        const float dp_dx = (pxp - pxm) * I2DX;
        const float dp_dy = (apyp[e] - apym[e]) * I2DY;
        const float dp_dz = (apzp[e] - apzm[e]) * I2DZ;

        const float div = du_dx + dv_dy + dw_dz;

        const float lap_u = (uxp - 2.f * u  + uxm) * IDX2 + (auyp[e] - 2.f * u  + auym[e]) * IDY2 + (auzp[e] - 2.f * u  + auzm[e]) * IDZ2;
        const float lap_v = (vxp - 2.f * v  + vxm) * IDX2 + (avyp[e] - 2.f * v  + avym[e]) * IDY2 + (avzp[e] - 2.f * v  + avzm[e]) * IDZ2;
        const float lap_w = (wxp - 2.f * wq + wxm) * IDX2 + (awyp[e] - 2.f * wq + awym[e]) * IDY2 + (awzp[e] - 2.f * wq + awzm[e]) * IDZ2;

        const float rx = u * du_dx + v * du_dy + wq * du_dz + dp_dx - INV_RE * lap_u;
        const float ry = u * dv_dx + v * dv_dy + wq * dv_dz + dp_dy - INV_RE * lap_v;
        const float rz = u * dw_dx + v * dw_dy + wq * dw_dz + dp_dz - INV_RE * lap_w;

        const bool wIn = (w >= 1) & (w <= Wn - 2);
        const float m = (s > 0.f && wIn && hIn && dIn) ? CCM : 0.f;
        acc += m * (div * div + rx * rx + ry * ry + rz * rz);
    }

    // outlet (w==63 vs w==62: both in lane x==15's registers)
    if (x == 15) {
        const float a0 = au[3] - au[2];
        const float a1 = av[3] - av[2];
        const float a2 = aw[3] - aw[2];
        acc += CO * (a0 * a0 + a1 * a1 + a2 * a2);
    }

    // ct term (one thread in the whole grid)
    if (blockIdx.y == 0 && blockIdx.z == 0 &&
        threadIdx.x == 0 && threadIdx.y == 0 && threadIdx.z == 0) {
        float t = 0.f;
        for (int i = 0; i < Bn; ++i) {
            const float dc = ct[i] - gt_ct[i];
            t += dc * dc;
        }
        acc += CCT * t;
    }

    // wave64 reduce -> LDS -> one atomic per block
    for (int off = 32; off > 0; off >>= 1)
        acc += __shfl_down(acc, off);

    __shared__ float wsum[4];
    const int tid  = (threadIdx.z * 4 + threadIdx.y) * 16 + threadIdx.x;
    const int wid  = tid >> 6;
    const int lane = tid & 63;
    if (lane == 0) wsum[wid] = acc;
    __syncthreads();
    if (tid == 0)
        atomicAdd(out, wsum[0] + wsum[1] + wsum[2] + wsum[3]);
}

extern "C" void kernel_launch(void* const* d_in, const int* in_sizes, int n_in,
                              void* d_out, int out_size, void* d_ws, size_t ws_size,
                              hipStream_t stream) {
    const float* field    = (const float*)d_in[0];
    const float* ct       = (const float*)d_in[1];
    const float* gt_field = (const float*)d_in[2];
    const float* gt_ct    = (const float*)d_in[3];
    const float* sdf      = (const float*)d_in[4];
    float* out = (float*)d_out;

    hipMemsetAsync(out, 0, (size_t)out_size * sizeof(float), stream);

    dim3 block(16, 4, 4);
    dim3 grid(1, Hn / 4, (Dn / 4) * Bn);   // (1, 32, 128)
    hipLaunchKernelGGL(fno3d_loss_kernel, grid, block, 0, stream,
                       field, ct, gt_field, gt_ct, sdf, out);
}

// Round 4
// 170.636 us; speedup vs baseline: 1.9521x; 1.0548x over previous
//
#include <hip/hip_runtime.h>

// Geometry (compile-time, from reference)
constexpr int Bn = 8, Dn = 64, Hn = 128, Wn = 64;
constexpr int sH = Wn;                 // 64
constexpr int sD = Hn * Wn;            // 8192
constexpr int sC = Dn * sD;            // 524288
constexpr int sB = 4 * sC;             // 2097152

// Grid spacings
constexpr double DXd = 2.5 / 63.0;
constexpr double DYd = 1.0 / 127.0;
constexpr double DZd = 0.8 / 63.0;

constexpr float I2DX = (float)(0.5 / DXd);
constexpr float I2DY = (float)(0.5 / DYd);
constexpr float I2DZ = (float)(0.5 / DZd);
constexpr float IDX2 = (float)(1.0 / (DXd * DXd));
constexpr float IDY2 = (float)(1.0 / (DYd * DYd));
constexpr float IDZ2 = (float)(1.0 / (DZd * DZd));
constexpr float INV_RE = 1.0e-6f;

// weights / counts
constexpr float CF  = (float)(1.0  / (8.0 * 4.0 * 64.0 * 128.0 * 64.0));
constexpr float CCT = (float)(10.0 / 8.0);
constexpr float CCM = (float)(1.0  / (8.0 * 62.0 * 126.0 * 62.0));
constexpr float CN  = (float)(10.0 / (8.0 * 64.0 * 128.0 * 64.0));
constexpr float CI  = (float)(5.0  / (8.0 * 64.0 * 128.0));
constexpr float CO  = (float)(1.0  / (8.0 * 64.0 * 128.0));

__device__ __forceinline__ float4 ld4(const float* __restrict__ p, int off) {
    return *reinterpret_cast<const float4*>(p + off);
}

// Main kernel: z-march stencil. Block (16,8)=128 thr (2 waves); each thread
// owns (w0..w0+3, h) and marches 8 consecutive d-planes. 1024 blocks total.
__global__ __launch_bounds__(128, 2) void fno3d_main(
    const float* __restrict__ field,
    const float* __restrict__ gt_field,
    const float* __restrict__ sdf,
    float* __restrict__ partials)
{
    const int x   = threadIdx.x;            // 0..15
    const int ty  = threadIdx.y;            // 0..7
    const int blk = blockIdx.x;             // 0..1023
    const int b   = blk >> 7;               // 8 batches
    const int rem = blk & 127;
    const int d0  = (rem >> 4) << 3;        // 8 segments of 8 planes
    const int h   = ((rem & 15) << 3) + ty; // 16 h-tiles of 8 rows
    const int w0  = x << 2;

    const float* Fb = field    + b * sB;
    const float* Gb = gt_field + b * sB;
    const float* Sb = sdf      + b * sC;

    const int hm = (h > 0)      ? h - 1 : h;
    const int hp = (h < Hn - 1) ? h + 1 : h;
    const bool hIn = (h >= 1) & (h <= Hn - 2);

    const int rowc = h  * sH + w0;
    const int rowm = hm * sH + w0;
    const int rowp = hp * sH + w0;

    // ---- prologue: planes d0-1 (prev), d0 (cur), d0+1 (nxt) centers;
    //      gt+sdf for plane d0 ----
    const int dm0 = (d0 > 0) ? d0 - 1 : 0;
    const int dn0 = (d0 < Dn - 1) ? d0 + 1 : d0;

    float4 pU = ld4(Fb, dm0 * sD + rowc);
    float4 pV = ld4(Fb, sC + dm0 * sD + rowc);
    float4 pW = ld4(Fb, 2 * sC + dm0 * sD + rowc);
    float4 cU = ld4(Fb, d0 * sD + rowc);
    float4 cV = ld4(Fb, sC + d0 * sD + rowc);
    float4 cW = ld4(Fb, 2 * sC + d0 * sD + rowc);
    float4 cP = ld4(Fb, 3 * sC + d0 * sD + rowc);
    float4 nU = ld4(Fb, dn0 * sD + rowc);
    float4 nV = ld4(Fb, sC + dn0 * sD + rowc);
    float4 nW = ld4(Fb, 2 * sC + dn0 * sD + rowc);
    float4 nP = ld4(Fb, 3 * sC + dn0 * sD + rowc);
    // prev/nxt P planes (only needed for z-derivative of p? no: dp_dz uses
    // p at d±1 -> yes needed)
    float4 pP = ld4(Fb, 3 * sC + dm0 * sD + rowc);

    float4 cGU = ld4(Gb, d0 * sD + rowc);
    float4 cGV = ld4(Gb, sC + d0 * sD + rowc);
    float4 cGW = ld4(Gb, 2 * sC + d0 * sD + rowc);
    float4 cGP = ld4(Gb, 3 * sC + d0 * sD + rowc);
    float4 cS  = ld4(Sb, d0 * sD + rowc);

    float acc = 0.f;

    #pragma unroll
    for (int k = 0; k < 8; ++k) {
        const int d   = d0 + k;
        const int dn  = (d < Dn - 1) ? d + 1 : d;   // plane of nxt (already held)
        const int dnn = (dn < Dn - 1) ? dn + 1 : dn; // plane d+2 (prefetch)

        // ---- issue cold prefetches: centers(d+2), gt(d+1), sdf(d+1) ----
        const float4 qU = ld4(Fb, dnn * sD + rowc);
        const float4 qV = ld4(Fb, sC + dnn * sD + rowc);
        const float4 qW = ld4(Fb, 2 * sC + dnn * sD + rowc);
        const float4 qP = ld4(Fb, 3 * sC + dnn * sD + rowc);
        const float4 nGU = ld4(Gb, dn * sD + rowc);
        const float4 nGV = ld4(Gb, sC + dn * sD + rowc);
        const float4 nGW = ld4(Gb, 2 * sC + dn * sD + rowc);
        const float4 nGP = ld4(Gb, 3 * sC + dn * sD + rowc);
        const float4 nS  = ld4(Sb, dn * sD + rowc);

        // ---- warm y-neighbor loads for plane d ----
        const float4 uym = ld4(Fb, d * sD + rowm), uyp = ld4(Fb, d * sD + rowp);
        const float4 vym = ld4(Fb, sC + d * sD + rowm), vyp = ld4(Fb, sC + d * sD + rowp);
        const float4 wym = ld4(Fb, 2 * sC + d * sD + rowm), wyp = ld4(Fb, 2 * sC + d * sD + rowp);
        const float4 pym = ld4(Fb, 3 * sC + d * sD + rowm), pyp = ld4(Fb, 3 * sC + d * sD + rowp);

        // ---- x-neighbors across lanes ----
        const float uLs = __shfl_up(cU.w, 1), uRs = __shfl_down(cU.x, 1);
        const float vLs = __shfl_up(cV.w, 1), vRs = __shfl_down(cV.x, 1);
        const float wLs = __shfl_up(cW.w, 1), wRs = __shfl_down(cW.x, 1);
        const float pLs = __shfl_up(cP.w, 1), pRs = __shfl_down(cP.x, 1);

        const float* au = (const float*)&cU; const float* av = (const float*)&cV;
        const float* aw = (const float*)&cW; const float* ap = (const float*)&cP;
        const float* apu = (const float*)&pU; const float* apv = (const float*)&pV;
        const float* apw = (const float*)&pW; const float* app = (const float*)&pP;
        const float* anu = (const float*)&nU; const float* anv = (const float*)&nV;
        const float* anw = (const float*)&nW; const float* anp = (const float*)&nP;
        const float* agu = (const float*)&cGU; const float* agv = (const float*)&cGV;
        const float* agw = (const float*)&cGW; const float* agp = (const float*)&cGP;
        const float* as_ = (const float*)&cS;
        const float* ayum = (const float*)&uym; const float* ayup = (const float*)&uyp;
        const float* ayvm = (const float*)&vym; const float* ayvp = (const float*)&vyp;
        const float* aywm = (const float*)&wym; const float* aywp = (const float*)&wyp;
        const float* aypm = (const float*)&pym; const float* aypp = (const float*)&pyp;

        const bool dIn = (d >= 1) & (d <= Dn - 2);

        #pragma unroll
        for (int e = 0; e < 4; ++e) {
            const int w = w0 + e;
            const float u = au[e], v = av[e], wq = aw[e], pq = ap[e];

            // field MSE
            {
                const float e0 = u  - agu[e];
                const float e1 = v  - agv[e];
                const float e2 = wq - agw[e];
                const float e3 = pq - agp[e];
                acc += CF * (e0 * e0 + e1 * e1 + e2 * e2 + e3 * e3);
            }

            const float s = as_[e];

            // no-slip (solid)
            acc += ((s <= 0.f) ? CN : 0.f) * (u * u + v * v + wq * wq);

            // inlet (w==0)
            {
                const float du = u - 1.0f;
                acc += ((w == 0) ? CI : 0.f) * (du * du + v * v + wq * wq);
            }

            // interior continuity + momentum
            const float uxm = (e == 0) ? uLs : au[e - 1];
            const float uxp = (e == 3) ? uRs : au[e + 1];
            const float vxm = (e == 0) ? vLs : av[e - 1];
            const float vxp = (e == 3) ? vRs : av[e + 1];
            const float wxm = (e == 0) ? wLs : aw[e - 1];
            const float wxp = (e == 3) ? wRs : aw[e + 1];
            const float pxm = (e == 0) ? pLs : ap[e - 1];
            const float pxp = (e == 3) ? pRs : ap[e + 1];

            const float du_dx = (uxp - uxm) * I2DX;
            const float du_dy = (ayup[e] - ayum[e]) * I2DY;
            const float du_dz = (anu[e] - apu[e]) * I2DZ;
            const float dv_dx = (vxp - vxm) * I2DX;
            const float dv_dy = (ayvp[e] - ayvm[e]) * I2DY;
            const float dv_dz = (anv[e] - apv[e]) * I2DZ;
            const float dw_dx = (wxp - wxm) * I2DX;
            const float dw_dy = (aywp[e] - aywm[e]) * I2DY;
            const float dw_dz = (anw[e] - apw[e]) * I2DZ;
            const float dp_dx = (pxp - pxm) * I2DX;
            const float dp_dy = (aypp[e] - aypm[e]) * I2DY;
            const float dp_dz = (anp[e] - app[e]) * I2DZ;

            const float div = du_dx + dv_dy + dw_dz;

            const float lap_u = (uxp - 2.f * u  + uxm) * IDX2 + (ayup[e] - 2.f * u  + ayum[e]) * IDY2 + (anu[e] - 2.f * u  + apu[e]) * IDZ2;
            const float lap_v = (vxp - 2.f * v  + vxm) * IDX2 + (ayvp[e] - 2.f * v  + ayvm[e]) * IDY2 + (anv[e] - 2.f * v  + apv[e]) * IDZ2;
            const float lap_w = (wxp - 2.f * wq + wxm) * IDX2 + (aywp[e] - 2.f * wq + aywm[e]) * IDY2 + (anw[e] - 2.f * wq + apw[e]) * IDZ2;

            const float rx = u * du_dx + v * du_dy + wq * du_dz + dp_dx - INV_RE * lap_u;
            const float ry = u * dv_dx + v * dv_dy + wq * dv_dz + dp_dy - INV_RE * lap_v;
            const float rz = u * dw_dx + v * dw_dy + wq * dw_dz + dp_dz - INV_RE * lap_w;

            const bool wIn = (w >= 1) & (w <= Wn - 2);
            const float m = (s > 0.f && wIn && hIn && dIn) ? CCM : 0.f;
            acc += m * (div * div + rx * rx + ry * ry + rz * rz);
        }

        // outlet (w==63 vs w==62, lane x==15), every (b,d,h)
        if (x == 15) {
            const float a0 = au[3] - au[2];
            const float a1 = av[3] - av[2];
            const float a2 = aw[3] - aw[2];
            acc += CO * (a0 * a0 + a1 * a1 + a2 * a2);
        }

        // ---- rotate pipeline registers ----
        pU = cU; pV = cV; pW = cW; pP = cP;
        cU = nU; cV = nV; cW = nW; cP = nP;
        nU = qU; nV = qV; nW = qW; nP = qP;
        cGU = nGU; cGV = nGV; cGW = nGW; cGP = nGP;
        cS = nS;
    }

    // reduce 2 waves -> one partial per block (no atomics)
    for (int off = 32; off > 0; off >>= 1)
        acc += __shfl_down(acc, off);

    __shared__ float wsum[2];
    const int tid  = threadIdx.y * 16 + threadIdx.x;
    const int wid  = tid >> 6;
    const int lane = tid & 63;
    if (lane == 0) wsum[wid] = acc;
    __syncthreads();
    if (tid == 0) partials[blk] = wsum[0] + wsum[1];
}

// Final reduce: 1024 partials + ct term -> out[0]
__global__ __launch_bounds__(256) void fno3d_reduce(
    const float* __restrict__ partials,
    const float* __restrict__ ct,
    const float* __restrict__ gt_ct,
    float* __restrict__ out)
{
    const int t = threadIdx.x;
    float s = partials[t] + partials[t + 256] + partials[t + 512] + partials[t + 768];
    for (int off = 32; off > 0; off >>= 1)
        s += __shfl_down(s, off);

    __shared__ float wsum[4];
    if ((t & 63) == 0) wsum[t >> 6] = s;
    __syncthreads();
    if (t == 0) {
        float tot = wsum[0] + wsum[1] + wsum[2] + wsum[3];
        float ctl = 0.f;
        for (int i = 0; i < Bn; ++i) {
            const float dc = ct[i] - gt_ct[i];
            ctl += dc * dc;
        }
        out[0] = tot + CCT * ctl;
    }
}

extern "C" void kernel_launch(void* const* d_in, const int* in_sizes, int n_in,
                              void* d_out, int out_size, void* d_ws, size_t ws_size,
                              hipStream_t stream) {
    const float* field    = (const float*)d_in[0];
    const float* ct       = (const float*)d_in[1];
    const float* gt_field = (const float*)d_in[2];
    const float* gt_ct    = (const float*)d_in[3];
    const float* sdf      = (const float*)d_in[4];
    float* out      = (float*)d_out;
    float* partials = (float*)d_ws;   // 1024 floats = 4 KiB of scratch

    hipLaunchKernelGGL(fno3d_main, dim3(1024), dim3(16, 8, 1), 0, stream,
                       field, gt_field, sdf, partials);
    hipLaunchKernelGGL(fno3d_reduce, dim3(1), dim3(256), 0, stream,
                       partials, ct, gt_ct, out);
}